// Round 1
// baseline (395.084 us; speedup 1.0000x reference)
//
#include <hip/hip_runtime.h>
#include <math.h>

// Problem: x [32,512,512,1] f32, w [1,8] f32 -> y [32,512,512,1] f32.
// Reference collapses to per-row (W-axis) circular convolution with
// g = IDFT_512( 1/|Hhat(v)|^4 ),  Hhat(v) = sum_{j<8} w[j] e^{-2pi i v j/512}.
// g is real & even (|Hhat(-v)| = |Hhat(v)|).

#define NROWS 16384   // 32 * 512
#define WDIM  512

// ---------------------------------------------------------------------------
// Kernel 1: build g[n], n = blockIdx.x in [0,512). 512 threads, one per v.
// Double precision: G(v)=1/|H|^4 can be huge; the 512-term cosine sum has
// heavy cancellation -> fp32 would risk O(1..30) absolute error in g.
// ---------------------------------------------------------------------------
__global__ __launch_bounds__(512) void build_g_kernel(const float* __restrict__ w,
                                                      float* __restrict__ g) {
    const int n = blockIdx.x;
    const int v = threadIdx.x;
    const double TWO_PI_OVER_W = 6.2831853071795864769 / 512.0;

    // Hhat(v) over the 8 taps (exact mod-512 argument reduction).
    double hr = 0.0, hi = 0.0;
    #pragma unroll
    for (int j = 0; j < 8; ++j) {
        double wj = (double)w[j];
        double ang = TWO_PI_OVER_W * (double)((v * j) & 511);
        hr += wj * cos(ang);
        hi -= wj * sin(ang);
    }
    double mag2 = hr * hr + hi * hi;
    double G = 1.0 / (mag2 * mag2);          // 1/|H|^4, real

    // term of IDFT at output n (sin parts cancel since G is even).
    double term = G * cos(TWO_PI_OVER_W * (double)((v * n) & 511));

    __shared__ double red[512];
    red[v] = term;
    __syncthreads();
    #pragma unroll
    for (int s = 256; s > 0; s >>= 1) {
        if (v < s) red[v] += red[v + s];
        __syncthreads();
    }
    if (v == 0) g[n] = (float)(red[0] * (1.0 / 512.0));
}

// ---------------------------------------------------------------------------
// Kernel 2: y[r,n] = sum_k g[k] * x[r, (n-k) mod 512].
// One block per row, 128 threads, 4 consecutive outputs per thread.
// Row stored twice in LDS so the index (n-k+512) needs no mod.
// Per 4-k group: 2 lane-contiguous float4 x-reads + 1 broadcast float4 g-read
// feed 16 FMAs. All LDS reads conflict-free.
// ---------------------------------------------------------------------------
__global__ __launch_bounds__(128) void conv_rows_kernel(const float* __restrict__ x,
                                                        const float* __restrict__ g,
                                                        float* __restrict__ y) {
    __shared__ __align__(16) float xe[1024];
    __shared__ __align__(16) float gs[512];

    const int r = blockIdx.x;
    const int t = threadIdx.x;
    const float* xrow = x + (size_t)r * WDIM;

    #pragma unroll
    for (int i = t; i < WDIM; i += 128) {
        float v = xrow[i];
        xe[i]       = v;
        xe[i + 512] = v;
        gs[i]       = g[i];
    }
    __syncthreads();

    const int n0 = 4 * t;
    float a0 = 0.f, a1 = 0.f, a2 = 0.f, a3 = 0.f;

    #pragma unroll 4
    for (int k = 0; k < 512; k += 4) {
        const int c = n0 + 512 - k;   // multiple of 4; c in [4, 1020]
        float4 xa = *reinterpret_cast<const float4*>(&xe[c - 4]); // xe[c-4..c-1]
        float4 xb = *reinterpret_cast<const float4*>(&xe[c]);     // xe[c..c+3]
        float4 gk = *reinterpret_cast<const float4*>(&gs[k]);     // g[k..k+3]
        // output n0+j, tap k+i uses xe[c + j - i]
        a0 += gk.x * xb.x;  a0 += gk.y * xa.w;  a0 += gk.z * xa.z;  a0 += gk.w * xa.y;
        a1 += gk.x * xb.y;  a1 += gk.y * xb.x;  a1 += gk.z * xa.w;  a1 += gk.w * xa.z;
        a2 += gk.x * xb.z;  a2 += gk.y * xb.y;  a2 += gk.z * xb.x;  a2 += gk.w * xa.w;
        a3 += gk.x * xb.w;  a3 += gk.y * xb.z;  a3 += gk.z * xb.y;  a3 += gk.w * xb.x;
    }

    float4 outv = make_float4(a0, a1, a2, a3);
    *reinterpret_cast<float4*>(&y[(size_t)r * WDIM + n0]) = outv;
}

extern "C" void kernel_launch(void* const* d_in, const int* in_sizes, int n_in,
                              void* d_out, int out_size, void* d_ws, size_t ws_size,
                              hipStream_t stream) {
    const float* x = (const float*)d_in[0];   // [32,512,512,1]
    const float* w = (const float*)d_in[1];   // [1,8]
    float* y = (float*)d_out;
    float* g = (float*)d_ws;                  // 512 floats of scratch

    build_g_kernel<<<dim3(WDIM), dim3(512), 0, stream>>>(w, g);
    conv_rows_kernel<<<dim3(NROWS), dim3(128), 0, stream>>>(x, g, y);
}

// Round 2
// 91.187 us; speedup vs baseline: 4.3327x; 4.3327x over previous
//
#include <hip/hip_runtime.h>
#include <math.h>

// x [32,512,512,1] f32, w [1,8] f32 -> y [32,512,512,1] f32.
// Reference == per-row 512-pt circular conv with real spectrum G(v)=1/|H(v)|^4,
// H(v) = sum_{j<8} w[j] e^{-2pi i v j/512}.
// Pack two rows as z = x1 + i*x2. Since G is real: W(v) = G(v) Z(v), and
// y1 = Re(ifft(W)), y2 = Im(ifft(W)).  Forward radix-8 DIF (natural in ->
// digit-reversed out) pairs with inverse radix-8 DIT (digit-reversed in ->
// natural out); G is stored digit-reversed so no reorder pass exists.

#define WDIM 512
#define PAIRS_PER_BLOCK 4   // 4 independent waves per block, one row-pair each

struct cplx { float re, im; };
__device__ __forceinline__ cplx cadd(cplx a, cplx b) { return {a.re + b.re, a.im + b.im}; }
__device__ __forceinline__ cplx csub(cplx a, cplx b) { return {a.re - b.re, a.im - b.im}; }
__device__ __forceinline__ cplx cmul(cplx a, cplx b) {
    return {a.re * b.re - a.im * b.im, a.re * b.im + a.im * b.re};
}
// multiply by SIGN*i  (SIGN=-1 forward FFT, +1 inverse)
template <int SIGN> __device__ __forceinline__ cplx cmul_i(cplx a) {
    return (SIGN > 0) ? cplx{-a.im, a.re} : cplx{a.im, -a.re};
}

// 8-point DFT, b_t = sum_j a_j * w8^(j t), w8 = e^(SIGN*2pi i/8).
template <int SIGN> __device__ __forceinline__ void dft8(const cplx* a, cplx* b) {
    cplx t0 = cadd(a[0], a[4]), t4 = csub(a[0], a[4]);
    cplx t1 = cadd(a[1], a[5]), t5 = csub(a[1], a[5]);
    cplx t2 = cadd(a[2], a[6]), t6 = cmul_i<SIGN>(csub(a[2], a[6]));
    cplx t3 = cadd(a[3], a[7]), t7 = cmul_i<SIGN>(csub(a[3], a[7]));
    cplx E0 = cadd(t0, t2), E2 = csub(t0, t2);
    cplx E1 = cadd(t4, t6), E3 = csub(t4, t6);
    cplx O0 = cadd(t1, t3), O2 = csub(t1, t3);
    cplx O1 = cadd(t5, t7), O3 = csub(t5, t7);
    const float C = 0.70710678118654752f;
    cplx w1 = {C, SIGN * C};    // w8^1
    cplx w3 = {-C, SIGN * C};   // w8^3
    cplx O1w = cmul(O1, w1);
    cplx O2w = cmul_i<SIGN>(O2);
    cplx O3w = cmul(O3, w3);
    b[0] = cadd(E0, O0);  b[4] = csub(E0, O0);
    b[1] = cadd(E1, O1w); b[5] = csub(E1, O1w);
    b[2] = cadd(E2, O2w); b[6] = csub(E2, O2w);
    b[3] = cadd(E3, O3w); b[7] = csub(E3, O3w);
}

// b[t] *= e^(SIGN * i * theta * t), t=0..7 (theta >= 0)
template <int SIGN> __device__ __forceinline__ void twiddle8(cplx* b, float theta) {
    float sn, cs;
    __sincosf(theta, &sn, &cs);
    cplx w = {cs, SIGN * sn};
    cplx wt = w;
    b[1] = cmul(b[1], wt);
#pragma unroll
    for (int t = 2; t < 8; ++t) { wt = cmul(wt, w); b[t] = cmul(b[t], wt); }
}

// LDS address swizzle: q -> q + 4*(q>>6). Makes all three stage patterns
// (stride 64 / mixed 64-8 / stride 1 per thread) at most 2-way bank aliased.
__device__ __forceinline__ int phi(int q) { return q + ((q >> 6) << 2); }

// ---------------------------------------------------------------------------
// G in digit-reversed order: Gdr[p] = 1/|H(dr3(p))|^4 (double precision).
// ---------------------------------------------------------------------------
__global__ __launch_bounds__(512) void build_gdr_kernel(const float* __restrict__ w,
                                                        float* __restrict__ Gdr) {
    const int p = threadIdx.x;
    const int k = ((p & 7) << 6) | (p & 56) | (p >> 6);  // base-8 digit reversal
    const double step = 6.283185307179586476925286766559 / 512.0;
    double hr = 0.0, hi = 0.0;
#pragma unroll
    for (int j = 0; j < 8; ++j) {
        double wj = (double)w[j];
        double ang = step * (double)((k * j) & 511);
        hr += wj * cos(ang);
        hi -= wj * sin(ang);
    }
    double m2 = hr * hr + hi * hi;
    Gdr[p] = (float)(1.0 / (m2 * m2));
}

// ---------------------------------------------------------------------------
// One wave (64 lanes) = one row-pair. Thread u owns elements {u + 64j}.
// Stages: [regs] fwd m=512 -> LDS -> fwd m=64 -> LDS -> (fwd m=8 · G · inv m=8,
// all in regs) -> LDS -> inv m=64 -> LDS -> inv m=512 [regs] -> global.
// ---------------------------------------------------------------------------
__global__ __launch_bounds__(256) void fft_conv_kernel(const float* __restrict__ x,
                                                       const float* __restrict__ Gdr,
                                                       float* __restrict__ y) {
    __shared__ float lds[PAIRS_PER_BLOCK][2][544];
    const int wv = threadIdx.x >> 6;
    const int u = threadIdx.x & 63;
    const int pair = blockIdx.x * PAIRS_PER_BLOCK + wv;
    float* lre = lds[wv][0];
    float* lim = lds[wv][1];
    const float* x1 = x + (size_t)(2 * pair) * WDIM;
    const float* x2 = x1 + WDIM;

    const float STEP512 = 6.283185307179586f / 512.0f;
    const float STEP64 = 6.283185307179586f / 64.0f;

    cplx a[8], b[8];
#pragma unroll
    for (int j = 0; j < 8; ++j) {
        int idx = u + 64 * j;
        a[j].re = x1[idx];
        a[j].im = x2[idx];
    }

    // ---- forward DIF, m=512 (regs -> LDS) ----
    dft8<-1>(a, b);
    twiddle8<-1>(b, STEP512 * (float)u);
#pragma unroll
    for (int t = 0; t < 8; ++t) {
        int p = phi(u + 64 * t);
        lre[p] = b[t].re; lim[p] = b[t].im;
    }
    __syncthreads();

    // ---- forward DIF, m=64 ----
    {
        const int base = ((u >> 3) << 6) + (u & 7);
#pragma unroll
        for (int j = 0; j < 8; ++j) {
            int p = phi(base + 8 * j);
            a[j].re = lre[p]; a[j].im = lim[p];
        }
        dft8<-1>(a, b);
        twiddle8<-1>(b, STEP64 * (float)(u & 7));
#pragma unroll
        for (int t = 0; t < 8; ++t) {
            int p = phi(base + 8 * t);
            lre[p] = b[t].re; lim[p] = b[t].im;
        }
    }
    __syncthreads();

    // ---- fwd m=8  ·  pointwise G (digit-reversed spectrum)  ·  inv m=8 ----
    {
        const int base = 8 * u;
#pragma unroll
        for (int j = 0; j < 8; ++j) {
            int p = phi(base + j);
            a[j].re = lre[p]; a[j].im = lim[p];
        }
        dft8<-1>(a, b);
#pragma unroll
        for (int t = 0; t < 8; ++t) {
            float gv = Gdr[base + t];
            b[t].re *= gv; b[t].im *= gv;
        }
        dft8<+1>(b, a);
#pragma unroll
        for (int j = 0; j < 8; ++j) {
            int p = phi(base + j);
            lre[p] = a[j].re; lim[p] = a[j].im;
        }
    }
    __syncthreads();

    // ---- inverse DIT, m=64 (twiddle BEFORE butterfly) ----
    {
        const int base = ((u >> 3) << 6) + (u & 7);
#pragma unroll
        for (int t = 0; t < 8; ++t) {
            int p = phi(base + 8 * t);
            a[t].re = lre[p]; a[t].im = lim[p];
        }
        twiddle8<+1>(a, STEP64 * (float)(u & 7));
        dft8<+1>(a, b);
#pragma unroll
        for (int j = 0; j < 8; ++j) {
            int p = phi(base + 8 * j);
            lre[p] = b[j].re; lim[p] = b[j].im;
        }
    }
    __syncthreads();

    // ---- inverse DIT, m=512 (LDS -> regs -> global), scale 1/512 ----
    {
#pragma unroll
        for (int t = 0; t < 8; ++t) {
            int p = phi(u + 64 * t);
            a[t].re = lre[p]; a[t].im = lim[p];
        }
        twiddle8<+1>(a, STEP512 * (float)u);
        dft8<+1>(a, b);
        const float s = 1.0f / 512.0f;
        float* y1 = y + (size_t)(2 * pair) * WDIM;
        float* y2 = y1 + WDIM;
#pragma unroll
        for (int j = 0; j < 8; ++j) {
            int idx = u + 64 * j;
            y1[idx] = b[j].re * s;
            y2[idx] = b[j].im * s;
        }
    }
}

extern "C" void kernel_launch(void* const* d_in, const int* in_sizes, int n_in,
                              void* d_out, int out_size, void* d_ws, size_t ws_size,
                              hipStream_t stream) {
    const float* x = (const float*)d_in[0];  // [32,512,512,1]
    const float* w = (const float*)d_in[1];  // [1,8]
    float* y = (float*)d_out;
    float* Gdr = (float*)d_ws;  // 512 floats scratch

    build_gdr_kernel<<<dim3(1), dim3(512), 0, stream>>>(w, Gdr);
    fft_conv_kernel<<<dim3(16384 / (2 * PAIRS_PER_BLOCK)), dim3(256), 0, stream>>>(x, Gdr, y);
}

// Round 3
// 88.614 us; speedup vs baseline: 4.4585x; 1.0290x over previous
//
#include <hip/hip_runtime.h>
#include <math.h>

// x [32,512,512,1] f32, w [1,8] f32 -> y [32,512,512,1] f32.
// Reference == per-row 512-pt circular conv with real spectrum G(v)=1/|H(v)|^4,
// H(v) = sum_{j<8} w[j] e^{-2pi i v j/512}.
// Pack two rows as z = x1 + i*x2. Since G is real: W(v) = G(v) Z(v), and
// y1 = Re(ifft(W)), y2 = Im(ifft(W)).  Forward radix-8 DIF (natural in ->
// digit-reversed out) pairs with inverse radix-8 DIT (digit-reversed in ->
// natural out); the pointwise G multiply happens in digit-reversed order,
// with each thread's 8 G values computed INLINE via one 8-pt DFT of its
// twiddled taps (no separate build kernel, no G global traffic).

#define WDIM 512
#define PAIRS_PER_BLOCK 4   // 4 independent waves per block, one row-pair each

struct cplx { float re, im; };
__device__ __forceinline__ cplx cadd(cplx a, cplx b) { return {a.re + b.re, a.im + b.im}; }
__device__ __forceinline__ cplx csub(cplx a, cplx b) { return {a.re - b.re, a.im - b.im}; }
__device__ __forceinline__ cplx cmul(cplx a, cplx b) {
    return {a.re * b.re - a.im * b.im, a.re * b.im + a.im * b.re};
}
// multiply by SIGN*i  (SIGN=-1 forward FFT, +1 inverse)
template <int SIGN> __device__ __forceinline__ cplx cmul_i(cplx a) {
    return (SIGN > 0) ? cplx{-a.im, a.re} : cplx{a.im, -a.re};
}

// 8-point DFT, b_t = sum_j a_j * w8^(j t), w8 = e^(SIGN*2pi i/8).
template <int SIGN> __device__ __forceinline__ void dft8(const cplx* a, cplx* b) {
    cplx t0 = cadd(a[0], a[4]), t4 = csub(a[0], a[4]);
    cplx t1 = cadd(a[1], a[5]), t5 = csub(a[1], a[5]);
    cplx t2 = cadd(a[2], a[6]), t6 = cmul_i<SIGN>(csub(a[2], a[6]));
    cplx t3 = cadd(a[3], a[7]), t7 = cmul_i<SIGN>(csub(a[3], a[7]));
    cplx E0 = cadd(t0, t2), E2 = csub(t0, t2);
    cplx E1 = cadd(t4, t6), E3 = csub(t4, t6);
    cplx O0 = cadd(t1, t3), O2 = csub(t1, t3);
    cplx O1 = cadd(t5, t7), O3 = csub(t5, t7);
    const float C = 0.70710678118654752f;
    cplx w1 = {C, SIGN * C};    // w8^1
    cplx w3 = {-C, SIGN * C};   // w8^3
    cplx O1w = cmul(O1, w1);
    cplx O2w = cmul_i<SIGN>(O2);
    cplx O3w = cmul(O3, w3);
    b[0] = cadd(E0, O0);  b[4] = csub(E0, O0);
    b[1] = cadd(E1, O1w); b[5] = csub(E1, O1w);
    b[2] = cadd(E2, O2w); b[6] = csub(E2, O2w);
    b[3] = cadd(E3, O3w); b[7] = csub(E3, O3w);
}

// b[t] *= e^(SIGN * i * theta * t), t=0..7 (theta >= 0)
template <int SIGN> __device__ __forceinline__ void twiddle8(cplx* b, float theta) {
    float sn, cs;
    __sincosf(theta, &sn, &cs);
    cplx w = {cs, SIGN * sn};
    cplx wt = w;
    b[1] = cmul(b[1], wt);
#pragma unroll
    for (int t = 2; t < 8; ++t) { wt = cmul(wt, w); b[t] = cmul(b[t], wt); }
}

// LDS address swizzle: q -> q + 4*(q>>6). Makes all three stage patterns
// (stride 64 / mixed 64-8 / stride 1 per thread) at most 2-way bank aliased.
__device__ __forceinline__ int phi(int q) { return q + ((q >> 6) << 2); }

// ---------------------------------------------------------------------------
// One wave (64 lanes) = one row-pair. Thread u owns elements {u + 64j}.
// Stages: [regs] fwd m=512 -> LDS -> fwd m=64 -> LDS -> (fwd m=8 · G · inv m=8,
// all in regs, G inline) -> LDS -> inv m=64 -> LDS -> inv m=512 [regs] -> global.
// ---------------------------------------------------------------------------
__global__ __launch_bounds__(256) void fft_conv_kernel(const float* __restrict__ x,
                                                       const float* __restrict__ w,
                                                       float* __restrict__ y) {
    __shared__ float lds[PAIRS_PER_BLOCK][2][544];
    const int wv = threadIdx.x >> 6;
    const int u = threadIdx.x & 63;
    const int pair = blockIdx.x * PAIRS_PER_BLOCK + wv;
    float* lre = lds[wv][0];
    float* lim = lds[wv][1];
    const float* x1 = x + (size_t)(2 * pair) * WDIM;
    const float* x2 = x1 + WDIM;

    const float STEP512 = 6.283185307179586f / 512.0f;
    const float STEP64 = 6.283185307179586f / 64.0f;

    cplx a[8], b[8];
#pragma unroll
    for (int j = 0; j < 8; ++j) {
        int idx = u + 64 * j;
        a[j].re = x1[idx];
        a[j].im = x2[idx];
    }

    // ---- inline G: this thread needs Gdr[8u+t] = G(64t + c), c = 8(u&7)+(u>>3).
    // H(64t+c) = sum_j (w_j e^{-i*STEP512*c*j}) * w8^{tj}  -> one dft8 over
    // the twiddled taps yields all 8 H values; G = 1/|H|^4.
    // Issued here so the ~110 VALU ops hide under the global-load latency.
    float Gv[8];
    {
        const int c = ((u & 7) << 3) + (u >> 3);
        cplx m[8], Hv[8];
#pragma unroll
        for (int j = 0; j < 8; ++j) {
            float sn, cs;
            __sincosf(STEP512 * (float)((c * j) & 511), &sn, &cs);
            float wj = w[j];
            m[j].re = wj * cs;
            m[j].im = -wj * sn;
        }
        dft8<-1>(m, Hv);
#pragma unroll
        for (int t = 0; t < 8; ++t) {
            float m2 = Hv[t].re * Hv[t].re + Hv[t].im * Hv[t].im;
            Gv[t] = 1.0f / (m2 * m2);
        }
    }

    // ---- forward DIF, m=512 (regs -> LDS) ----
    dft8<-1>(a, b);
    twiddle8<-1>(b, STEP512 * (float)u);
#pragma unroll
    for (int t = 0; t < 8; ++t) {
        int p = phi(u + 64 * t);
        lre[p] = b[t].re; lim[p] = b[t].im;
    }
    __syncthreads();

    // ---- forward DIF, m=64 ----
    {
        const int base = ((u >> 3) << 6) + (u & 7);
#pragma unroll
        for (int j = 0; j < 8; ++j) {
            int p = phi(base + 8 * j);
            a[j].re = lre[p]; a[j].im = lim[p];
        }
        dft8<-1>(a, b);
        twiddle8<-1>(b, STEP64 * (float)(u & 7));
#pragma unroll
        for (int t = 0; t < 8; ++t) {
            int p = phi(base + 8 * t);
            lre[p] = b[t].re; lim[p] = b[t].im;
        }
    }
    __syncthreads();

    // ---- fwd m=8  ·  pointwise G (digit-reversed spectrum)  ·  inv m=8 ----
    {
        const int base = 8 * u;
#pragma unroll
        for (int j = 0; j < 8; ++j) {
            int p = phi(base + j);
            a[j].re = lre[p]; a[j].im = lim[p];
        }
        dft8<-1>(a, b);
#pragma unroll
        for (int t = 0; t < 8; ++t) {
            b[t].re *= Gv[t]; b[t].im *= Gv[t];
        }
        dft8<+1>(b, a);
#pragma unroll
        for (int j = 0; j < 8; ++j) {
            int p = phi(base + j);
            lre[p] = a[j].re; lim[p] = a[j].im;
        }
    }
    __syncthreads();

    // ---- inverse DIT, m=64 (twiddle BEFORE butterfly) ----
    {
        const int base = ((u >> 3) << 6) + (u & 7);
#pragma unroll
        for (int t = 0; t < 8; ++t) {
            int p = phi(base + 8 * t);
            a[t].re = lre[p]; a[t].im = lim[p];
        }
        twiddle8<+1>(a, STEP64 * (float)(u & 7));
        dft8<+1>(a, b);
#pragma unroll
        for (int j = 0; j < 8; ++j) {
            int p = phi(base + 8 * j);
            lre[p] = b[j].re; lim[p] = b[j].im;
        }
    }
    __syncthreads();

    // ---- inverse DIT, m=512 (LDS -> regs -> global), scale 1/512 ----
    {
#pragma unroll
        for (int t = 0; t < 8; ++t) {
            int p = phi(u + 64 * t);
            a[t].re = lre[p]; a[t].im = lim[p];
        }
        twiddle8<+1>(a, STEP512 * (float)u);
        dft8<+1>(a, b);
        const float s = 1.0f / 512.0f;
        float* y1 = y + (size_t)(2 * pair) * WDIM;
        float* y2 = y1 + WDIM;
#pragma unroll
        for (int j = 0; j < 8; ++j) {
            int idx = u + 64 * j;
            y1[idx] = b[j].re * s;
            y2[idx] = b[j].im * s;
        }
    }
}

extern "C" void kernel_launch(void* const* d_in, const int* in_sizes, int n_in,
                              void* d_out, int out_size, void* d_ws, size_t ws_size,
                              hipStream_t stream) {
    const float* x = (const float*)d_in[0];  // [32,512,512,1]
    const float* w = (const float*)d_in[1];  // [1,8]
    float* y = (float*)d_out;

    fft_conv_kernel<<<dim3(16384 / (2 * PAIRS_PER_BLOCK)), dim3(256), 0, stream>>>(x, w, y);
}

// Round 4
// 88.361 us; speedup vs baseline: 4.4712x; 1.0029x over previous
//
#include <hip/hip_runtime.h>

// x [32,512,512,1] f32, w [1,8] f32 -> y [32,512,512,1] f32.
// Reference == per-row 512-pt circular conv with real spectrum G(v)=1/|H(v)|^4,
// H(v) = sum_{j<8} w[j] e^{-2pi i v j/512}.
// Pack two rows as z = x1 + i*x2. Since G is real: W(v) = G(v) Z(v), and
// y1 = Re(ifft(W)), y2 = Im(ifft(W)).  Forward radix-8 DIF (natural in ->
// digit-reversed out) pairs with inverse radix-8 DIT (digit-reversed in ->
// natural out); G multiply happens digit-reversed, computed inline per thread.
//
// All twiddle angles are exact rationals k/512 revolutions -> native
// v_sin_f32/v_cos_f32 (input in REVOLUTIONS per gfx950 ISA), no OCML sincos,
// no range reduction, no cmul twiddle chains.

#define WDIM 512
#define PAIRS_PER_BLOCK 4   // 4 independent waves per block, one row-pair each

struct cplx { float re, im; };
__device__ __forceinline__ cplx cadd(cplx a, cplx b) { return {a.re + b.re, a.im + b.im}; }
__device__ __forceinline__ cplx csub(cplx a, cplx b) { return {a.re - b.re, a.im - b.im}; }
__device__ __forceinline__ cplx cmul(cplx a, cplx b) {
    return {a.re * b.re - a.im * b.im, a.re * b.im + a.im * b.re};
}
// multiply by SIGN*i  (SIGN=-1 forward FFT, +1 inverse)
template <int SIGN> __device__ __forceinline__ cplx cmul_i(cplx a) {
    return (SIGN > 0) ? cplx{-a.im, a.re} : cplx{a.im, -a.re};
}

// e^{SIGN * 2*pi*i * k/512}, k in [0,512) — native trig, exact argument.
template <int SIGN> __device__ __forceinline__ cplx wroot512(int k) {
    float f = (float)k * (1.0f / 512.0f);
    float sn = __builtin_amdgcn_sinf(f);   // sin(2*pi*f)
    float cs = __builtin_amdgcn_cosf(f);   // cos(2*pi*f)
    return {cs, SIGN > 0 ? sn : -sn};
}

// 8-point DFT, b_t = sum_j a_j * w8^(j t), w8 = e^(SIGN*2pi i/8).
template <int SIGN> __device__ __forceinline__ void dft8(const cplx* a, cplx* b) {
    cplx t0 = cadd(a[0], a[4]), t4 = csub(a[0], a[4]);
    cplx t1 = cadd(a[1], a[5]), t5 = csub(a[1], a[5]);
    cplx t2 = cadd(a[2], a[6]), t6 = cmul_i<SIGN>(csub(a[2], a[6]));
    cplx t3 = cadd(a[3], a[7]), t7 = cmul_i<SIGN>(csub(a[3], a[7]));
    cplx E0 = cadd(t0, t2), E2 = csub(t0, t2);
    cplx E1 = cadd(t4, t6), E3 = csub(t4, t6);
    cplx O0 = cadd(t1, t3), O2 = csub(t1, t3);
    cplx O1 = cadd(t5, t7), O3 = csub(t5, t7);
    const float C = 0.70710678118654752f;
    cplx w1 = {C, SIGN * C};    // w8^1
    cplx w3 = {-C, SIGN * C};   // w8^3
    cplx O1w = cmul(O1, w1);
    cplx O2w = cmul_i<SIGN>(O2);
    cplx O3w = cmul(O3, w3);
    b[0] = cadd(E0, O0);  b[4] = csub(E0, O0);
    b[1] = cadd(E1, O1w); b[5] = csub(E1, O1w);
    b[2] = cadd(E2, O2w); b[6] = csub(E2, O2w);
    b[3] = cadd(E3, O3w); b[7] = csub(E3, O3w);
}

// b[t] *= e^{SIGN*2pi i * (k512*t)/512}, t=1..7. Direct per-t native trig:
// independent (no serial cmul chain), exact arguments. k512*7 < 512 ok, but
// mask anyway for safety.
template <int SIGN> __device__ __forceinline__ void twiddle8(cplx* b, int k512) {
#pragma unroll
    for (int t = 1; t < 8; ++t) {
        cplx w = wroot512<SIGN>((k512 * t) & 511);
        b[t] = cmul(b[t], w);
    }
}

// LDS address swizzle: q -> q + 4*(q>>6). Keeps stage patterns low-conflict.
__device__ __forceinline__ int phi(int q) { return q + ((q >> 6) << 2); }

// ---------------------------------------------------------------------------
// One wave (64 lanes) = one row-pair. Thread u owns elements {u + 64j}.
// Stages: [regs] fwd m=512 -> LDS -> fwd m=64 -> LDS -> (fwd m=8 · G · inv m=8,
// all in regs, G inline) -> LDS -> inv m=64 -> LDS -> inv m=512 [regs] -> global.
// ---------------------------------------------------------------------------
__global__ __launch_bounds__(256, 4) void fft_conv_kernel(const float* __restrict__ x,
                                                          const float* __restrict__ w,
                                                          float* __restrict__ y) {
    __shared__ float lds[PAIRS_PER_BLOCK][2][544];
    const int wv = threadIdx.x >> 6;
    const int u = threadIdx.x & 63;
    const int pair = blockIdx.x * PAIRS_PER_BLOCK + wv;
    float* lre = lds[wv][0];
    float* lim = lds[wv][1];
    const float* x1 = x + (size_t)(2 * pair) * WDIM;
    const float* x2 = x1 + WDIM;

    cplx a[8], b[8];
#pragma unroll
    for (int j = 0; j < 8; ++j) {
        int idx = u + 64 * j;
        a[j].re = x1[idx];
        a[j].im = x2[idx];
    }

    // ---- inline G: this thread needs Gdr[8u+t] = G(64t + c), c = 8(u&7)+(u>>3).
    // H(64t+c) = sum_j (w_j e^{-2pi i c j/512}) * w8^{tj} -> one dft8 over the
    // twiddled taps yields all 8 H values; G = 1/|H|^4. Hidden under load latency.
    float Gv[8];
    {
        const int c = ((u & 7) << 3) + (u >> 3);
        cplx m[8], Hv[8];
        m[0] = {w[0], 0.0f};
#pragma unroll
        for (int j = 1; j < 8; ++j) {
            cplx e = wroot512<-1>((c * j) & 511);
            float wj = w[j];
            m[j].re = wj * e.re;
            m[j].im = wj * e.im;
        }
        dft8<-1>(m, Hv);
#pragma unroll
        for (int t = 0; t < 8; ++t) {
            float m2 = Hv[t].re * Hv[t].re + Hv[t].im * Hv[t].im;
            Gv[t] = 1.0f / (m2 * m2);
        }
    }

    // ---- forward DIF, m=512 (regs -> LDS); twiddle step = u/512 rev ----
    dft8<-1>(a, b);
    twiddle8<-1>(b, u);
#pragma unroll
    for (int t = 0; t < 8; ++t) {
        int p = phi(u + 64 * t);
        lre[p] = b[t].re; lim[p] = b[t].im;
    }
    __syncthreads();

    // ---- forward DIF, m=64; twiddle step = (u&7)/64 rev = 8*(u&7)/512 ----
    {
        const int base = ((u >> 3) << 6) + (u & 7);
#pragma unroll
        for (int j = 0; j < 8; ++j) {
            int p = phi(base + 8 * j);
            a[j].re = lre[p]; a[j].im = lim[p];
        }
        dft8<-1>(a, b);
        twiddle8<-1>(b, 8 * (u & 7));
#pragma unroll
        for (int t = 0; t < 8; ++t) {
            int p = phi(base + 8 * t);
            lre[p] = b[t].re; lim[p] = b[t].im;
        }
    }
    __syncthreads();

    // ---- fwd m=8  ·  pointwise G (digit-reversed spectrum)  ·  inv m=8 ----
    {
        const int base = 8 * u;
#pragma unroll
        for (int j = 0; j < 8; ++j) {
            int p = phi(base + j);
            a[j].re = lre[p]; a[j].im = lim[p];
        }
        dft8<-1>(a, b);
#pragma unroll
        for (int t = 0; t < 8; ++t) {
            b[t].re *= Gv[t]; b[t].im *= Gv[t];
        }
        dft8<+1>(b, a);
#pragma unroll
        for (int j = 0; j < 8; ++j) {
            int p = phi(base + j);
            lre[p] = a[j].re; lim[p] = a[j].im;
        }
    }
    __syncthreads();

    // ---- inverse DIT, m=64 (twiddle BEFORE butterfly) ----
    {
        const int base = ((u >> 3) << 6) + (u & 7);
#pragma unroll
        for (int t = 0; t < 8; ++t) {
            int p = phi(base + 8 * t);
            a[t].re = lre[p]; a[t].im = lim[p];
        }
        twiddle8<+1>(a, 8 * (u & 7));
        dft8<+1>(a, b);
#pragma unroll
        for (int j = 0; j < 8; ++j) {
            int p = phi(base + 8 * j);
            lre[p] = b[j].re; lim[p] = b[j].im;
        }
    }
    __syncthreads();

    // ---- inverse DIT, m=512 (LDS -> regs -> global), scale 1/512 ----
    {
#pragma unroll
        for (int t = 0; t < 8; ++t) {
            int p = phi(u + 64 * t);
            a[t].re = lre[p]; a[t].im = lim[p];
        }
        twiddle8<+1>(a, u);
        dft8<+1>(a, b);
        const float s = 1.0f / 512.0f;
        float* y1 = y + (size_t)(2 * pair) * WDIM;
        float* y2 = y1 + WDIM;
#pragma unroll
        for (int j = 0; j < 8; ++j) {
            int idx = u + 64 * j;
            y1[idx] = b[j].re * s;
            y2[idx] = b[j].im * s;
        }
    }
}

extern "C" void kernel_launch(void* const* d_in, const int* in_sizes, int n_in,
                              void* d_out, int out_size, void* d_ws, size_t ws_size,
                              hipStream_t stream) {
    const float* x = (const float*)d_in[0];  // [32,512,512,1]
    const float* w = (const float*)d_in[1];  // [1,8]
    float* y = (float*)d_out;

    fft_conv_kernel<<<dim3(16384 / (2 * PAIRS_PER_BLOCK)), dim3(256), 0, stream>>>(x, w, y);
}

// Round 5
// 87.060 us; speedup vs baseline: 4.5381x; 1.0149x over previous
//
#include <hip/hip_runtime.h>

// x [32,512,512,1] f32, w [1,8] f32 -> y [32,512,512,1] f32.
// Reference == per-row 512-pt circular conv with real spectrum G(v)=1/|H(v)|^4,
// H(v) = sum_{j<8} w[j] e^{-2pi i v j/512}.
// Pack two rows as z = x1 + i*x2; G real => y1 = Re(ifft(G*fft(z))), y2 = Im.
// Radix-8 DIF forward (natural -> digit-reversed) + radix-8 DIT inverse
// (digit-reversed -> natural); G is precomputed in digit-reversed order with
// the 1/512 IFFT scale folded in.
//
// R5 changes vs R4:
//  - G precomputed by a tiny kernel into d_ws (frees ~40 VGPRs in the main
//    kernel -> no scratch spill at the 128-VGPR cap; spill traffic was the
//    prime suspect for the unexplained ~40us).
//  - 64-thread single-wave blocks: no s_barrier is emitted for WG<=wave,
//    only the lgkmcnt memory fence (wave-private LDS region).
//  - Per-stage-pair LDS swizzles: +4*(q>>6) for 64-stride pairs (2-way, free),
//    +2*(q>>6) for 8-stride pairs (worst 4-way vs previous 8-way).

#define WDIM 512

struct cplx { float re, im; };
__device__ __forceinline__ cplx cadd(cplx a, cplx b) { return {a.re + b.re, a.im + b.im}; }
__device__ __forceinline__ cplx csub(cplx a, cplx b) { return {a.re - b.re, a.im - b.im}; }
__device__ __forceinline__ cplx cmul(cplx a, cplx b) {
    return {a.re * b.re - a.im * b.im, a.re * b.im + a.im * b.re};
}
template <int SIGN> __device__ __forceinline__ cplx cmul_i(cplx a) {
    return (SIGN > 0) ? cplx{-a.im, a.re} : cplx{a.im, -a.re};
}

// e^{SIGN * 2*pi*i * k/512} — native v_sin/v_cos take REVOLUTIONS (exact arg).
template <int SIGN> __device__ __forceinline__ cplx wroot512(int k) {
    float f = (float)k * (1.0f / 512.0f);
    float sn = __builtin_amdgcn_sinf(f);
    float cs = __builtin_amdgcn_cosf(f);
    return {cs, SIGN > 0 ? sn : -sn};
}

// 8-point DFT, b_t = sum_j a_j w8^{jt}, w8 = e^{SIGN*2pi i/8}.
template <int SIGN> __device__ __forceinline__ void dft8(const cplx* a, cplx* b) {
    cplx t0 = cadd(a[0], a[4]), t4 = csub(a[0], a[4]);
    cplx t1 = cadd(a[1], a[5]), t5 = csub(a[1], a[5]);
    cplx t2 = cadd(a[2], a[6]), t6 = cmul_i<SIGN>(csub(a[2], a[6]));
    cplx t3 = cadd(a[3], a[7]), t7 = cmul_i<SIGN>(csub(a[3], a[7]));
    cplx E0 = cadd(t0, t2), E2 = csub(t0, t2);
    cplx E1 = cadd(t4, t6), E3 = csub(t4, t6);
    cplx O0 = cadd(t1, t3), O2 = csub(t1, t3);
    cplx O1 = cadd(t5, t7), O3 = csub(t5, t7);
    const float C = 0.70710678118654752f;
    cplx w1 = {C, SIGN * C};
    cplx w3 = {-C, SIGN * C};
    cplx O1w = cmul(O1, w1);
    cplx O2w = cmul_i<SIGN>(O2);
    cplx O3w = cmul(O3, w3);
    b[0] = cadd(E0, O0);  b[4] = csub(E0, O0);
    b[1] = cadd(E1, O1w); b[5] = csub(E1, O1w);
    b[2] = cadd(E2, O2w); b[6] = csub(E2, O2w);
    b[3] = cadd(E3, O3w); b[7] = csub(E3, O3w);
}

// b[t] *= e^{SIGN*2pi i * k512*t/512}, t=1..7 (k512*7 < 512, args exact).
template <int SIGN> __device__ __forceinline__ void twiddle8(cplx* b, int k512) {
#pragma unroll
    for (int t = 1; t < 8; ++t) {
        cplx w = wroot512<SIGN>(k512 * t);
        b[t] = cmul(b[t], w);
    }
}

// Swizzles: A-pairs (stride-64 patterns) use +4*(q>>6); B-pairs (stride-8
// patterns) use +2*(q>>6). Max index 511+28=539 -> plane size 544.
__device__ __forceinline__ int phiA(int q) { return q + ((q >> 6) << 2); }
__device__ __forceinline__ int phiB(int q) { return q + ((q >> 6) << 1); }

// ---------------------------------------------------------------------------
// Gdr[p] = (1/512) / |H(dr3(p))|^4, digit-reversed, fp32 native trig.
// ---------------------------------------------------------------------------
__global__ __launch_bounds__(512) void build_gdr_kernel(const float* __restrict__ w,
                                                        float* __restrict__ Gdr) {
    const int p = threadIdx.x;
    const int k = ((p & 7) << 6) | (p & 56) | (p >> 6);
    float hr = 0.f, hi = 0.f;
#pragma unroll
    for (int j = 0; j < 8; ++j) {
        float f = (float)((k * j) & 511) * (1.0f / 512.0f);
        float wj = w[j];
        hr += wj * __builtin_amdgcn_cosf(f);
        hi -= wj * __builtin_amdgcn_sinf(f);
    }
    float m2 = hr * hr + hi * hi;
    Gdr[p] = (1.0f / 512.0f) / (m2 * m2);
}

// ---------------------------------------------------------------------------
// One 64-thread block = one wave = one row-pair. Thread u owns {u + 64j}.
// [regs] fwd m=512 -> LDS(A) -> fwd m=64 -> LDS(B) -> fwd m=8 · G · inv m=8
// -> LDS(B) -> inv m=64 -> LDS(A) -> inv m=512 [regs] -> global.
// ---------------------------------------------------------------------------
__global__ __launch_bounds__(64, 4) void fft_conv_kernel(const float* __restrict__ x,
                                                         const float* __restrict__ Gdr,
                                                         float* __restrict__ y) {
    __shared__ float lre[544];
    __shared__ float lim[544];
    const int u = threadIdx.x;
    const int pair = blockIdx.x;
    const float* x1 = x + (size_t)(2 * pair) * WDIM;
    const float* x2 = x1 + WDIM;

    cplx a[8], b[8];
#pragma unroll
    for (int j = 0; j < 8; ++j) {
        int idx = u + 64 * j;
        a[j].re = x1[idx];
        a[j].im = x2[idx];
    }

    // G for this thread's digit-reversed spectral slots [8u, 8u+8).
    float Gv[8];
#pragma unroll
    for (int t = 0; t < 8; ++t) Gv[t] = Gdr[8 * u + t];

    // ---- forward DIF, m=512 (regs -> LDS, swizzle A) ----
    dft8<-1>(a, b);
    twiddle8<-1>(b, u);
#pragma unroll
    for (int t = 0; t < 8; ++t) {
        int p = phiA(u + 64 * t);
        lre[p] = b[t].re; lim[p] = b[t].im;
    }
    __syncthreads();

    // ---- forward DIF, m=64 (read A, write B) ----
    {
        const int base = ((u >> 3) << 6) + (u & 7);
#pragma unroll
        for (int j = 0; j < 8; ++j) {
            int p = phiA(base + 8 * j);
            a[j].re = lre[p]; a[j].im = lim[p];
        }
        dft8<-1>(a, b);
        twiddle8<-1>(b, 8 * (u & 7));
        __syncthreads();   // A-reads done before B-writes overwrite slots
#pragma unroll
        for (int t = 0; t < 8; ++t) {
            int p = phiB(base + 8 * t);
            lre[p] = b[t].re; lim[p] = b[t].im;
        }
    }
    __syncthreads();

    // ---- fwd m=8 · G (digit-reversed) · inv m=8 (read B, write B) ----
    {
        const int base = 8 * u;
#pragma unroll
        for (int j = 0; j < 8; ++j) {
            int p = phiB(base + j);
            a[j].re = lre[p]; a[j].im = lim[p];
        }
        dft8<-1>(a, b);
#pragma unroll
        for (int t = 0; t < 8; ++t) {
            b[t].re *= Gv[t]; b[t].im *= Gv[t];
        }
        dft8<+1>(b, a);
#pragma unroll
        for (int j = 0; j < 8; ++j) {
            int p = phiB(base + j);
            lre[p] = a[j].re; lim[p] = a[j].im;
        }
    }
    __syncthreads();

    // ---- inverse DIT, m=64 (read B, write A; twiddle BEFORE butterfly) ----
    {
        const int base = ((u >> 3) << 6) + (u & 7);
#pragma unroll
        for (int t = 0; t < 8; ++t) {
            int p = phiB(base + 8 * t);
            a[t].re = lre[p]; a[t].im = lim[p];
        }
        twiddle8<+1>(a, 8 * (u & 7));
        dft8<+1>(a, b);
        __syncthreads();   // B-reads done before A-writes overwrite slots
#pragma unroll
        for (int j = 0; j < 8; ++j) {
            int p = phiA(base + 8 * j);
            lre[p] = b[j].re; lim[p] = b[j].im;
        }
    }
    __syncthreads();

    // ---- inverse DIT, m=512 (read A -> regs -> global); scale folded in G ----
    {
#pragma unroll
        for (int t = 0; t < 8; ++t) {
            int p = phiA(u + 64 * t);
            a[t].re = lre[p]; a[t].im = lim[p];
        }
        twiddle8<+1>(a, u);
        dft8<+1>(a, b);
        float* y1 = y + (size_t)(2 * pair) * WDIM;
        float* y2 = y1 + WDIM;
#pragma unroll
        for (int j = 0; j < 8; ++j) {
            int idx = u + 64 * j;
            y1[idx] = b[j].re;
            y2[idx] = b[j].im;
        }
    }
}

extern "C" void kernel_launch(void* const* d_in, const int* in_sizes, int n_in,
                              void* d_out, int out_size, void* d_ws, size_t ws_size,
                              hipStream_t stream) {
    const float* x = (const float*)d_in[0];  // [32,512,512,1]
    const float* w = (const float*)d_in[1];  // [1,8]
    float* y = (float*)d_out;
    float* Gdr = (float*)d_ws;               // 512 floats scratch

    build_gdr_kernel<<<dim3(1), dim3(512), 0, stream>>>(w, Gdr);
    fft_conv_kernel<<<dim3(8192), dim3(64), 0, stream>>>(x, Gdr, y);
}

// Round 6
// 86.924 us; speedup vs baseline: 4.5452x; 1.0016x over previous
//
#include <hip/hip_runtime.h>

// x [32,512,512,1] f32, w [1,8] f32 -> y [32,512,512,1] f32.
// Reference == per-row 512-pt circular conv with real spectrum G(v)=1/|H(v)|^4,
// H(v) = sum_{j<8} w[j] e^{-2pi i v j/512}.
// Pack two rows as z = x1 + i*x2; G real => y1 = Re(ifft(G*fft(z))), y2 = Im.
// Radix-8 DIF forward (natural -> digit-reversed) + radix-8 DIT inverse
// (digit-reversed -> natural); G applied digit-reversed, computed inline,
// 1/512 ifft scale folded into G.
//
// R6: (1) LDS as float2 (b64 ops, half the instruction count), one unified
// swizzle p=q+2(q>>6) -> all patterns at the b64 bank floor AND per-thread
// read-set==write-set per stage (no intra-stage fences; 4 fences total, no
// s_barrier at WG=64). (2) fwd/inv share twiddle tables (28 trig, reused
// conjugated). (3) G inline at center stage -> single graph node.

#define WDIM 512

struct cplx { float re, im; };
__device__ __forceinline__ cplx cadd(cplx a, cplx b) { return {a.re + b.re, a.im + b.im}; }
__device__ __forceinline__ cplx csub(cplx a, cplx b) { return {a.re - b.re, a.im - b.im}; }
__device__ __forceinline__ cplx cmul(cplx a, cplx b) {
    return {a.re * b.re - a.im * b.im, a.re * b.im + a.im * b.re};
}
template <int SIGN> __device__ __forceinline__ cplx cmul_i(cplx a) {
    return (SIGN > 0) ? cplx{-a.im, a.re} : cplx{a.im, -a.re};
}
// v * (c + i s)
__device__ __forceinline__ cplx twmul(cplx v, float c, float s) {
    return {v.re * c - v.im * s, v.im * c + v.re * s};
}

// 8-point DFT, b_t = sum_j a_j w8^{jt}, w8 = e^{SIGN*2pi i/8}.
template <int SIGN> __device__ __forceinline__ void dft8(const cplx* a, cplx* b) {
    cplx t0 = cadd(a[0], a[4]), t4 = csub(a[0], a[4]);
    cplx t1 = cadd(a[1], a[5]), t5 = csub(a[1], a[5]);
    cplx t2 = cadd(a[2], a[6]), t6 = cmul_i<SIGN>(csub(a[2], a[6]));
    cplx t3 = cadd(a[3], a[7]), t7 = cmul_i<SIGN>(csub(a[3], a[7]));
    cplx E0 = cadd(t0, t2), E2 = csub(t0, t2);
    cplx E1 = cadd(t4, t6), E3 = csub(t4, t6);
    cplx O0 = cadd(t1, t3), O2 = csub(t1, t3);
    cplx O1 = cadd(t5, t7), O3 = csub(t5, t7);
    const float C = 0.70710678118654752f;
    cplx w1 = {C, SIGN * C};
    cplx w3 = {-C, SIGN * C};
    cplx O1w = cmul(O1, w1);
    cplx O2w = cmul_i<SIGN>(O2);
    cplx O3w = cmul(O3, w3);
    b[0] = cadd(E0, O0);  b[4] = csub(E0, O0);
    b[1] = cadd(E1, O1w); b[5] = csub(E1, O1w);
    b[2] = cadd(E2, O2w); b[6] = csub(E2, O2w);
    b[3] = cadd(E3, O3w); b[7] = csub(E3, O3w);
}

// cplx-unit LDS swizzle; injective on [0,512); max 511+14=525 -> plane 528.
__device__ __forceinline__ int phi(int q) { return q + ((q >> 6) << 1); }

// ---------------------------------------------------------------------------
// One 64-thread (single-wave) block = one row-pair. Thread u owns {u + 64j}.
// [regs] fwd m=512 -> LDS -> fwd m=64 -> LDS -> fwd m=8 · G · inv m=8 ->
// LDS -> inv m=64 -> LDS -> inv m=512 [regs] -> global.
// ---------------------------------------------------------------------------
__global__ __launch_bounds__(64, 4) void fft_conv_kernel(const float* __restrict__ x,
                                                         const float* __restrict__ w,
                                                         float* __restrict__ y) {
    __shared__ float2 l[528];
    const int u = threadIdx.x;
    const int pair = blockIdx.x;
    const float* x1 = x + (size_t)(2 * pair) * WDIM;
    const float* x2 = x1 + WDIM;

    cplx a[8], b[8];
#pragma unroll
    for (int j = 0; j < 8; ++j) {
        int i = u + 64 * j;
        a[j].re = x1[i];
        a[j].im = x2[i];
    }

    // Shared twiddle tables (computed while the global loads are in flight;
    // native v_sin/v_cos take REVOLUTIONS, all arguments exact rationals).
    float c512[7], s512[7], c64[7], s64[7];
#pragma unroll
    for (int t = 1; t < 8; ++t) {
        float f = (float)(u * t) * (1.0f / 512.0f);
        s512[t - 1] = __builtin_amdgcn_sinf(f);
        c512[t - 1] = __builtin_amdgcn_cosf(f);
        float g = (float)((u & 7) * t) * (1.0f / 64.0f);
        s64[t - 1] = __builtin_amdgcn_sinf(g);
        c64[t - 1] = __builtin_amdgcn_cosf(g);
    }

    const int base = ((u >> 3) << 6) | (u & 7);

    // ---- forward DIF, m=512 (regs -> LDS) ----
    dft8<-1>(a, b);
#pragma unroll
    for (int t = 1; t < 8; ++t) b[t] = twmul(b[t], c512[t - 1], -s512[t - 1]);
#pragma unroll
    for (int t = 0; t < 8; ++t) l[phi(u + 64 * t)] = make_float2(b[t].re, b[t].im);
    __syncthreads();

    // ---- forward DIF, m=64 (in-place slot set per thread) ----
#pragma unroll
    for (int j = 0; j < 8; ++j) {
        float2 v = l[phi(base + 8 * j)];
        a[j].re = v.x; a[j].im = v.y;
    }
    dft8<-1>(a, b);
#pragma unroll
    for (int t = 1; t < 8; ++t) b[t] = twmul(b[t], c64[t - 1], -s64[t - 1]);
#pragma unroll
    for (int t = 0; t < 8; ++t) l[phi(base + 8 * t)] = make_float2(b[t].re, b[t].im);
    __syncthreads();

    // ---- inline G for digit-reversed slots [8u, 8u+8):
    // Gdr[8u+t] = G(64t+c), c = 8(u&7)+(u>>3); H(64t+c) = dft8 of twiddled taps.
    float Gv[8];
    {
        const int c = ((u & 7) << 3) | (u >> 3);
        cplx m[8], Hv[8];
        m[0].re = w[0]; m[0].im = 0.0f;
#pragma unroll
        for (int j = 1; j < 8; ++j) {
            float f = (float)(c * j) * (1.0f / 512.0f);
            float sn = __builtin_amdgcn_sinf(f);
            float cs = __builtin_amdgcn_cosf(f);
            float wj = w[j];
            m[j].re = wj * cs;
            m[j].im = -wj * sn;
        }
        dft8<-1>(m, Hv);
#pragma unroll
        for (int t = 0; t < 8; ++t) {
            float m2 = Hv[t].re * Hv[t].re + Hv[t].im * Hv[t].im;
            Gv[t] = (1.0f / 512.0f) / (m2 * m2);   // ifft scale folded in
        }
    }

    // ---- fwd m=8 · G · inv m=8 (in-place slot set per thread) ----
    {
        const int cb = 8 * u;
#pragma unroll
        for (int j = 0; j < 8; ++j) {
            float2 v = l[phi(cb + j)];
            a[j].re = v.x; a[j].im = v.y;
        }
        dft8<-1>(a, b);
#pragma unroll
        for (int t = 0; t < 8; ++t) { b[t].re *= Gv[t]; b[t].im *= Gv[t]; }
        dft8<+1>(b, a);
#pragma unroll
        for (int j = 0; j < 8; ++j) l[phi(cb + j)] = make_float2(a[j].re, a[j].im);
    }
    __syncthreads();

    // ---- inverse DIT, m=64 (twiddle BEFORE butterfly; in-place slots) ----
#pragma unroll
    for (int t = 0; t < 8; ++t) {
        float2 v = l[phi(base + 8 * t)];
        a[t].re = v.x; a[t].im = v.y;
    }
#pragma unroll
    for (int t = 1; t < 8; ++t) a[t] = twmul(a[t], c64[t - 1], s64[t - 1]);
    dft8<+1>(a, b);
#pragma unroll
    for (int j = 0; j < 8; ++j) l[phi(base + 8 * j)] = make_float2(b[j].re, b[j].im);
    __syncthreads();

    // ---- inverse DIT, m=512 (LDS -> regs -> global) ----
#pragma unroll
    for (int t = 0; t < 8; ++t) {
        float2 v = l[phi(u + 64 * t)];
        a[t].re = v.x; a[t].im = v.y;
    }
#pragma unroll
    for (int t = 1; t < 8; ++t) a[t] = twmul(a[t], c512[t - 1], s512[t - 1]);
    dft8<+1>(a, b);
    float* y1 = y + (size_t)(2 * pair) * WDIM;
    float* y2 = y1 + WDIM;
#pragma unroll
    for (int j = 0; j < 8; ++j) {
        int i = u + 64 * j;
        y1[i] = b[j].re;
        y2[i] = b[j].im;
    }
}

extern "C" void kernel_launch(void* const* d_in, const int* in_sizes, int n_in,
                              void* d_out, int out_size, void* d_ws, size_t ws_size,
                              hipStream_t stream) {
    const float* x = (const float*)d_in[0];  // [32,512,512,1]
    const float* w = (const float*)d_in[1];  // [1,8]
    float* y = (float*)d_out;

    fft_conv_kernel<<<dim3(8192), dim3(64), 0, stream>>>(x, w, y);
}